// Round 6
// baseline (145.555 us; speedup 1.0000x reference)
//
#include <hip/hip_runtime.h>

// Problem constants (fixed by reference)
#define BATCH   16384
#define NFEAT   512
#define NTREE   64
#define NDEPTH  6
#define NLEAF   64
#define NDOUT   64
#define NLOGIT  384   // NDEPTH * NTREE

typedef float    f32x4  __attribute__((ext_vector_type(4)));
typedef _Float16 half8  __attribute__((ext_vector_type(8)));
typedef _Float16 h2v    __attribute__((ext_vector_type(2)));
typedef __fp16   fp16x2 __attribute__((ext_vector_type(2)));

union H8 { _Float16 h[8]; half8 v; uint4 q; };
union H4 { _Float16 h[4]; ushort4 u; };

// async global->LDS DMA, 16B per lane; lds dest wave-uniform base,
// HW writes lane i at base + i*16 (m97/m104 semantics).
__device__ __forceinline__ void dma16(const void* g, void* l) {
    __builtin_amdgcn_global_load_lds(
        (const __attribute__((address_space(1))) unsigned int*)g,
        (__attribute__((address_space(3))) unsigned int*)l, 16, 0, 0);
}

// ---------------------------------------------------------------------------
// prep: blocks 0..63   -> V2[t][d][l] = f16(leaf[t][l][d] / 64)
//       blocks 64..159 -> Wt[n][f-blocks, groups-of-8 XOR-swizzled by n&7]
//                         = f16(W[d][f][t]),  n = d*64+t
// ---------------------------------------------------------------------------
__global__ __launch_bounds__(256) void prep(const float* __restrict__ leaf,
                                            const float* __restrict__ W,
                                            _Float16* __restrict__ V2,
                                            _Float16* __restrict__ Wt) {
    __shared__ float T[64 * 65];
    const int tid = threadIdx.x;
    if (blockIdx.x < 64) {
        const int t = blockIdx.x;
        const float* src = leaf + (size_t)t * 4096;
        for (int j = 0; j < 4; ++j) {
            int idx = tid + 256 * j;            // 0..1023 float4s
            int l = idx >> 4, d4 = idx & 15;
            float4 v = *(const float4*)(src + l * 64 + d4 * 4);
            T[l * 65 + d4 * 4 + 0] = v.x;
            T[l * 65 + d4 * 4 + 1] = v.y;
            T[l * 65 + d4 * 4 + 2] = v.z;
            T[l * 65 + d4 * 4 + 3] = v.w;
        }
        __syncthreads();
        _Float16* dst = V2 + (size_t)t * 4096;
        for (int j = 0; j < 4; ++j) {
            int idx = tid + 256 * j;
            int d = idx >> 4, l4 = idx & 15;
            H4 u;
            u.h[0] = (_Float16)(T[(l4 * 4 + 0) * 65 + d] * 0.015625f);
            u.h[1] = (_Float16)(T[(l4 * 4 + 1) * 65 + d] * 0.015625f);
            u.h[2] = (_Float16)(T[(l4 * 4 + 2) * 65 + d] * 0.015625f);
            u.h[3] = (_Float16)(T[(l4 * 4 + 3) * 65 + d] * 0.015625f);
            *(ushort4*)(dst + d * 64 + l4 * 4) = u.u;
        }
    } else {
        const int bid = blockIdx.x - 64;        // 0..95
        const int d = bid >> 4, f0 = (bid & 15) * 32;
        for (int j = 0; j < 2; ++j) {
            int idx = tid + 256 * j;            // 0..511 float4s (32 f x 64 t)
            int f = idx >> 4, c4 = idx & 15;
            float4 v = *(const float4*)(W + ((size_t)d * 512 + f0 + f) * 64 + c4 * 4);
            T[f * 65 + c4 * 4 + 0] = v.x;
            T[f * 65 + c4 * 4 + 1] = v.y;
            T[f * 65 + c4 * 4 + 2] = v.z;
            T[f * 65 + c4 * 4 + 3] = v.w;
        }
        __syncthreads();
        const int t = tid >> 2, c8 = tid & 3;
        H8 u;
        #pragma unroll
        for (int i = 0; i < 8; ++i) u.h[i] = (_Float16)T[(c8 * 8 + i) * 65 + t];
        int g  = ((f0 & 63) >> 3) + c8;         // k-group 0..7 in this 64-block
        int gs = g ^ (t & 7);                   // (n&7) == (t&7)
        *(half8*)(Wt + ((size_t)(d * 64 + t)) * 512 + (f0 & ~63) + gs * 8) = u.v;
    }
}

// ---------------------------------------------------------------------------
// fused: one block owns 64 batch rows END-TO-END.
//   Phase 1 (GEMM): logits for all 384 n over K=512, BK=64. B tiles DMA'd
//     from pre-swizzled Wt; A staged fp32->f16 once (cvt_pkrtz). 8 waves x
//     (64 rows x 48 n): mt4 nt3 ks2 = 24 MFMA/iter.
//   Phase 2 (trees): sigmoid -> Pn[n][row] in LDS (never leaves the block);
//     wave w owns trees [8w,8w+8) x 64 rows x 64 d; packed-f16 P build;
//     cross-wave combine via ds_add_f32 into sAcc; coalesced f32 out.
// LDS: phase1 As(8K)+Bs(48K)=56K; phase2 Pn(58.4K overlays)+sAcc(16.9K) = 75.3K.
// ---------------------------------------------------------------------------
__global__ __launch_bounds__(512, 2) void fused(const float* __restrict__ x,
                                                const _Float16* __restrict__ Wt,
                                                const float* __restrict__ bias,
                                                const _Float16* __restrict__ V2,
                                                float* __restrict__ out) {
    __shared__ __align__(16) char SM[75264];
    _Float16* As   = (_Float16*)SM;            // [64 r][64 k swz]   8192 B
    _Float16* Bs   = As + 4096;                // [384 n][64 k swz] 49152 B
    _Float16* Pn   = (_Float16*)SM;            // [384 n][76 row]   58368 B (overlay)
    float*    sAcc = (float*)(SM + 58368);     // [64 row][66 d]    16896 B

    const int tid  = threadIdx.x;
    const int w    = tid >> 6, lane = tid & 63;
    const int quad = lane >> 4, l15 = lane & 15;
    const int bm   = blockIdx.x;

    const int s_row = tid >> 3, s_c8 = tid & 7;    // A-stage: 64 rows x 8 grp
    const int b_r8  = lane >> 3, b_c8 = lane & 7;  // B-DMA lane mapping

    // ================= Phase 1: GEMM =================
    f32x4 acc[4][3];
    #pragma unroll
    for (int mt = 0; mt < 4; ++mt)
        #pragma unroll
        for (int nt = 0; nt < 3; ++nt)
            acc[mt][nt] = (f32x4){0.f, 0.f, 0.f, 0.f};

    for (int k0 = 0; k0 < NFEAT; k0 += 64) {
        // B stage: wave w stages n-rows [48w, 48w+48): 6 DMA x 1 KB
        #pragma unroll
        for (int i = 0; i < 6; ++i) {
            int nl = w * 48 + i * 8;
            const _Float16* g = Wt + (size_t)(nl + b_r8) * 512 + k0 + b_c8 * 8;
            dma16(g, (char*)Bs + (size_t)nl * 128);
        }
        // A stage: one half8 per thread, fp32->f16 once, XOR-swizzled
        {
            const float* src = x + (size_t)(bm * 64 + s_row) * NFEAT + k0 + s_c8 * 8;
            float4 v0 = *(const float4*)(src);
            float4 v1 = *(const float4*)(src + 4);
            H8 u;
            *(fp16x2*)&u.h[0] = __builtin_amdgcn_cvt_pkrtz(v0.x, v0.y);
            *(fp16x2*)&u.h[2] = __builtin_amdgcn_cvt_pkrtz(v0.z, v0.w);
            *(fp16x2*)&u.h[4] = __builtin_amdgcn_cvt_pkrtz(v1.x, v1.y);
            *(fp16x2*)&u.h[6] = __builtin_amdgcn_cvt_pkrtz(v1.z, v1.w);
            *(half8*)(As + s_row * 64 + ((s_c8 ^ (s_row & 7)) * 8)) = u.v;
        }
        __syncthreads();

        half8 bF[3][2];
        #pragma unroll
        for (int nt = 0; nt < 3; ++nt) {
            int n = w * 48 + nt * 16 + l15;
            #pragma unroll
            for (int ks = 0; ks < 2; ++ks) {
                int g = (ks * 4 + quad) ^ (n & 7);
                bF[nt][ks] = *(const half8*)(Bs + n * 64 + g * 8);
            }
        }
        half8 aF[4][2];
        #pragma unroll
        for (int mt = 0; mt < 4; ++mt) {
            int r = mt * 16 + l15;
            #pragma unroll
            for (int ks = 0; ks < 2; ++ks) {
                int g = (ks * 4 + quad) ^ (r & 7);
                aF[mt][ks] = *(const half8*)(As + r * 64 + g * 8);
            }
        }
        #pragma unroll
        for (int mt = 0; mt < 4; ++mt)
            #pragma unroll
            for (int nt = 0; nt < 3; ++nt)
                #pragma unroll
                for (int ks = 0; ks < 2; ++ks)
                    acc[mt][nt] = __builtin_amdgcn_mfma_f32_16x16x32_f16(
                        aF[mt][ks], bF[nt][ks], acc[mt][nt], 0, 0, 0);
        __syncthreads();
    }

    // ============ Transition: sigmoid -> Pn; zero sAcc ============
    // C/D layout: col(n)=l15, row = quad*4 + reg (+16*mt)
    #pragma unroll
    for (int nt = 0; nt < 3; ++nt) {
        int n = w * 48 + nt * 16 + l15;
        float bv = bias[n];
        #pragma unroll
        for (int mt = 0; mt < 4; ++mt) {
            int row = mt * 16 + quad * 4;
            H4 h;
            #pragma unroll
            for (int r = 0; r < 4; ++r) {
                float z = acc[mt][nt][r] + bv;
                h.h[r] = (_Float16)(1.0f / (1.0f + __expf(-z)));
            }
            *(ushort4*)(Pn + n * 76 + row) = h.u;
        }
    }
    #pragma unroll
    for (int j = 0; j < 9; ++j) {
        int idx = tid + 512 * j;
        if (idx < 64 * 66) sAcc[idx] = 0.f;
    }
    __syncthreads();

    // ================= Phase 2: trees =================
    f32x4 tac[4][4];
    #pragma unroll
    for (int mt = 0; mt < 4; ++mt)
        #pragma unroll
        for (int nt = 0; nt < 4; ++nt)
            tac[mt][nt] = (f32x4){0.f, 0.f, 0.f, 0.f};

    auto loadB = [&](int t, half8 (*bf)[2]) {
        #pragma unroll
        for (int nt = 0; nt < 4; ++nt)
            #pragma unroll
            for (int ks = 0; ks < 2; ++ks)
                bf[nt][ks] = *(const half8*)(V2 + (size_t)t * 4096 +
                                             (nt * 16 + l15) * 64 + ks * 32 + quad * 8);
    };
    const _Float16 one = (_Float16)1.0f;
    auto buildA = [&](int t, half8 (*af)[2]) {
        #pragma unroll
        for (int mt = 0; mt < 4; ++mt) {
            int rl = mt * 16 + l15;
            _Float16 p0 = Pn[(0 * 64 + t) * 76 + rl];
            _Float16 p1 = Pn[(1 * 64 + t) * 76 + rl];
            _Float16 p2 = Pn[(2 * 64 + t) * 76 + rl];
            _Float16 p3 = Pn[(3 * 64 + t) * 76 + rl];
            _Float16 p4 = Pn[(4 * 64 + t) * 76 + rl];
            _Float16 p5 = Pn[(5 * 64 + t) * 76 + rl];
            _Float16 q1 = (quad & 2) ? (_Float16)(one - p1) : p1;
            _Float16 q2 = (quad & 1) ? (_Float16)(one - p2) : p2;
            _Float16 pre  = q1 * q2;
            _Float16 pre0 = p0 * pre;
            _Float16 pre1 = (one - p0) * pre;
            h2v p4p = { p4, (_Float16)(one - p4) };
            h2v p5p = { p5, (_Float16)(one - p5) };
            h2v t34a = (h2v){ p3, p3 } * p4p;                       // t34[0],t34[1]
            _Float16 p3b = one - p3;
            h2v t34b = (h2v){ p3b, p3b } * p4p;                     // t34[2],t34[3]
            h2v w0 = (h2v){ t34a[0], t34a[0] } * p5p;
            h2v w1 = (h2v){ t34a[1], t34a[1] } * p5p;
            h2v w2 = (h2v){ t34b[0], t34b[0] } * p5p;
            h2v w3 = (h2v){ t34b[1], t34b[1] } * p5p;
            h2v P0 = { pre0, pre0 }, P1 = { pre1, pre1 };
            H8 a0, a1;
            *(h2v*)&a0.h[0] = P0 * w0; *(h2v*)&a0.h[2] = P0 * w1;
            *(h2v*)&a0.h[4] = P0 * w2; *(h2v*)&a0.h[6] = P0 * w3;
            *(h2v*)&a1.h[0] = P1 * w0; *(h2v*)&a1.h[2] = P1 * w1;
            *(h2v*)&a1.h[4] = P1 * w2; *(h2v*)&a1.h[6] = P1 * w3;
            af[mt][0] = a0.v;
            af[mt][1] = a1.v;
        }
    };

    half8 bA[4][2], bB[4][2], aF[4][2];
    loadB(w * 8, bA);
    for (int tl = 0; tl < 8; ++tl) {
        const int t = w * 8 + tl;
        half8 (*cur)[2] = (tl & 1) ? bB : bA;
        half8 (*nxt)[2] = (tl & 1) ? bA : bB;
        if (tl + 1 < 8) loadB(t + 1, nxt);    // in flight over the P build
        buildA(t, aF);
        #pragma unroll
        for (int mt = 0; mt < 4; ++mt)
            #pragma unroll
            for (int nt = 0; nt < 4; ++nt)
                #pragma unroll
                for (int ks = 0; ks < 2; ++ks)
                    tac[mt][nt] = __builtin_amdgcn_mfma_f32_16x16x32_f16(
                        aF[mt][ks], cur[nt][ks], tac[mt][nt], 0, 0, 0);
    }

    // cross-wave combine: ds_add_f32 (2 lanes/bank max = free)
    #pragma unroll
    for (int mt = 0; mt < 4; ++mt)
        #pragma unroll
        for (int nt = 0; nt < 4; ++nt)
            #pragma unroll
            for (int r = 0; r < 4; ++r)
                atomicAdd(&sAcc[(mt * 16 + quad * 4 + r) * 66 + nt * 16 + l15],
                          tac[mt][nt][r]);
    __syncthreads();

    // final store: thread -> (row, 8 d's), coalesced float4 x2
    {
        int row = tid >> 3, d8 = (tid & 7) * 8;
        const float* s = sAcc + row * 66 + d8;
        float4 o0 = { s[0], s[1], s[2], s[3] };
        float4 o1 = { s[4], s[5], s[6], s[7] };
        float* dst = out + (size_t)(bm * 64 + row) * NDOUT + d8;
        *(float4*)dst = o0;
        *(float4*)(dst + 4) = o1;
    }
}

// ---------------------------------------------------------------------------
extern "C" void kernel_launch(void* const* d_in, const int* in_sizes, int n_in,
                              void* d_out, int out_size, void* d_ws, size_t ws_size,
                              hipStream_t stream) {
    const float* x    = (const float*)d_in[0];  // (16384, 512)
    const float* W    = (const float*)d_in[1];  // (6, 512, 64)
    const float* bias = (const float*)d_in[2];  // (6, 64) flat = 384
    const float* leaf = (const float*)d_in[3];  // (64, 64, 64)
    float* out = (float*)d_out;                 // (16384, 64)

    // ws: V2 f16 (512 KB) | Wt f16 (384 KB)
    _Float16* V2 = (_Float16*)d_ws;
    _Float16* Wt = V2 + (size_t)NTREE * NLEAF * NDOUT;

    prep<<<160, 256, 0, stream>>>(leaf, W, V2, Wt);
    fused<<<BATCH / 64, 512, 0, stream>>>(x, Wt, bias, V2, out);
}

// Round 7
// 137.880 us; speedup vs baseline: 1.0557x; 1.0557x over previous
//
#include <hip/hip_runtime.h>

// Problem constants (fixed by reference)
#define BATCH   16384
#define NFEAT   512
#define NTREE   64
#define NDEPTH  6
#define NLEAF   64
#define NDOUT   64
#define NLOGIT  384   // NDEPTH * NTREE

typedef float    f32x4  __attribute__((ext_vector_type(4)));
typedef _Float16 half8  __attribute__((ext_vector_type(8)));
typedef _Float16 h2v    __attribute__((ext_vector_type(2)));
typedef __fp16   fp16x2 __attribute__((ext_vector_type(2)));

union H8 { _Float16 h[8]; half8 v; uint4 q; };
union H4 { _Float16 h[4]; ushort4 u; };

// async global->LDS DMA, 16B per lane; lds dest wave-uniform base,
// HW writes lane i at base + i*16 (m97/m104 semantics).
__device__ __forceinline__ void dma16(const void* g, void* l) {
    __builtin_amdgcn_global_load_lds(
        (const __attribute__((address_space(1))) unsigned int*)g,
        (__attribute__((address_space(3))) unsigned int*)l, 16, 0, 0);
}

// ---------------------------------------------------------------------------
// prep: blocks 0..63   -> V2[t][d][l] = f16(leaf[t][l][d] / 64)
//       blocks 64..159 -> Wt[n][f-blocks, groups-of-8 XOR-swizzled by n&7]
//                         = f16(W[d][f][t]),  n = d*64+t
// ---------------------------------------------------------------------------
__global__ __launch_bounds__(256) void prep(const float* __restrict__ leaf,
                                            const float* __restrict__ W,
                                            _Float16* __restrict__ V2,
                                            _Float16* __restrict__ Wt) {
    __shared__ float T[64 * 65];
    const int tid = threadIdx.x;
    if (blockIdx.x < 64) {
        const int t = blockIdx.x;
        const float* src = leaf + (size_t)t * 4096;
        for (int j = 0; j < 4; ++j) {
            int idx = tid + 256 * j;            // 0..1023 float4s
            int l = idx >> 4, d4 = idx & 15;
            float4 v = *(const float4*)(src + l * 64 + d4 * 4);
            T[l * 65 + d4 * 4 + 0] = v.x;
            T[l * 65 + d4 * 4 + 1] = v.y;
            T[l * 65 + d4 * 4 + 2] = v.z;
            T[l * 65 + d4 * 4 + 3] = v.w;
        }
        __syncthreads();
        _Float16* dst = V2 + (size_t)t * 4096;
        for (int j = 0; j < 4; ++j) {
            int idx = tid + 256 * j;
            int d = idx >> 4, l4 = idx & 15;
            H4 u;
            u.h[0] = (_Float16)(T[(l4 * 4 + 0) * 65 + d] * 0.015625f);
            u.h[1] = (_Float16)(T[(l4 * 4 + 1) * 65 + d] * 0.015625f);
            u.h[2] = (_Float16)(T[(l4 * 4 + 2) * 65 + d] * 0.015625f);
            u.h[3] = (_Float16)(T[(l4 * 4 + 3) * 65 + d] * 0.015625f);
            *(ushort4*)(dst + d * 64 + l4 * 4) = u.u;
        }
    } else {
        const int bid = blockIdx.x - 64;        // 0..95
        const int d = bid >> 4, f0 = (bid & 15) * 32;
        for (int j = 0; j < 2; ++j) {
            int idx = tid + 256 * j;            // 0..511 float4s (32 f x 64 t)
            int f = idx >> 4, c4 = idx & 15;
            float4 v = *(const float4*)(W + ((size_t)d * 512 + f0 + f) * 64 + c4 * 4);
            T[f * 65 + c4 * 4 + 0] = v.x;
            T[f * 65 + c4 * 4 + 1] = v.y;
            T[f * 65 + c4 * 4 + 2] = v.z;
            T[f * 65 + c4 * 4 + 3] = v.w;
        }
        __syncthreads();
        const int t = tid >> 2, c8 = tid & 3;
        H8 u;
        #pragma unroll
        for (int i = 0; i < 8; ++i) u.h[i] = (_Float16)T[(c8 * 8 + i) * 65 + t];
        int g  = ((f0 & 63) >> 3) + c8;         // k-group 0..7 in this 64-block
        int gs = g ^ (t & 7);                   // (n&7) == (t&7)
        *(half8*)(Wt + ((size_t)(d * 64 + t)) * 512 + (f0 & ~63) + gs * 8) = u.v;
    }
}

// ---------------------------------------------------------------------------
// fused v2: one block owns 32 batch rows end-to-end; 512 blocks = 2/CU
// (LDS 53.2 KB, __launch_bounds__(256,2)) so barrier drains of one block
// overlap the other block's MFMA.
//   Phase 1: all 384 logits for 32 rows, K=512, BK=64. B DMA'd from
//     pre-swizzled Wt; A staged fp32->f16 once. Wave tile 32r x 96n:
//     mt2 nt6 ks2 = 24 MFMA/iter.
//   Phase 2: sigmoid -> Pn[384][40] in LDS; wave w owns trees [16w,16w+16)
//     x 32 rows x 64 d; packed-f16 P build; bF double-buffered from L2-hot
//     V2; cross-wave combine via LDS f32 atomics; coalesced f32 stores.
// ---------------------------------------------------------------------------
__global__ __launch_bounds__(256, 2) void fused(const float* __restrict__ x,
                                                const _Float16* __restrict__ Wt,
                                                const float* __restrict__ bias,
                                                const _Float16* __restrict__ V2,
                                                float* __restrict__ out) {
    __shared__ __align__(16) char SM[53248];
    _Float16* As   = (_Float16*)SM;            // [32 r][64 k swz]   4096 B
    _Float16* Bs   = As + 2048;                // [384 n][64 k swz] 49152 B
    _Float16* Pn   = (_Float16*)SM;            // [384 n][40 row]   30720 B (overlay)
    float*    sAcc = (float*)(SM + 30720);     // [32 row][66 d]     8448 B

    const int tid  = threadIdx.x;
    const int w    = tid >> 6, lane = tid & 63;
    const int quad = lane >> 4, l15 = lane & 15;
    const int bm   = blockIdx.x;

    const int s_row = tid >> 3, s_c8 = tid & 7;    // A-stage: 32 rows x 8 grp
    const int b_r8  = lane >> 3, b_c8 = lane & 7;  // B-DMA lane mapping

    // ================= Phase 1: GEMM =================
    f32x4 acc[2][6];
    #pragma unroll
    for (int mt = 0; mt < 2; ++mt)
        #pragma unroll
        for (int nt = 0; nt < 6; ++nt)
            acc[mt][nt] = (f32x4){0.f, 0.f, 0.f, 0.f};

    for (int k0 = 0; k0 < NFEAT; k0 += 64) {
        // B stage: wave w stages n-rows [96w, 96w+96): 12 DMA x 1 KB
        #pragma unroll
        for (int i = 0; i < 12; ++i) {
            int nl = w * 96 + i * 8;
            const _Float16* g = Wt + (size_t)(nl + b_r8) * 512 + k0 + b_c8 * 8;
            dma16(g, (char*)Bs + (size_t)nl * 128);
        }
        // A stage: one half8 per thread, fp32->f16 once, XOR-swizzled
        {
            const float* src = x + (size_t)(bm * 32 + s_row) * NFEAT + k0 + s_c8 * 8;
            float4 v0 = *(const float4*)(src);
            float4 v1 = *(const float4*)(src + 4);
            H8 u;
            *(fp16x2*)&u.h[0] = __builtin_amdgcn_cvt_pkrtz(v0.x, v0.y);
            *(fp16x2*)&u.h[2] = __builtin_amdgcn_cvt_pkrtz(v0.z, v0.w);
            *(fp16x2*)&u.h[4] = __builtin_amdgcn_cvt_pkrtz(v1.x, v1.y);
            *(fp16x2*)&u.h[6] = __builtin_amdgcn_cvt_pkrtz(v1.z, v1.w);
            *(half8*)(As + s_row * 64 + ((s_c8 ^ (s_row & 7)) * 8)) = u.v;
        }
        __syncthreads();

        half8 bF[6][2];
        #pragma unroll
        for (int nt = 0; nt < 6; ++nt) {
            int n = w * 96 + nt * 16 + l15;
            #pragma unroll
            for (int ks = 0; ks < 2; ++ks) {
                int g = (ks * 4 + quad) ^ (n & 7);
                bF[nt][ks] = *(const half8*)(Bs + n * 64 + g * 8);
            }
        }
        half8 aF[2][2];
        #pragma unroll
        for (int mt = 0; mt < 2; ++mt) {
            int r = mt * 16 + l15;
            #pragma unroll
            for (int ks = 0; ks < 2; ++ks) {
                int g = (ks * 4 + quad) ^ (r & 7);
                aF[mt][ks] = *(const half8*)(As + r * 64 + g * 8);
            }
        }
        #pragma unroll
        for (int mt = 0; mt < 2; ++mt)
            #pragma unroll
            for (int nt = 0; nt < 6; ++nt)
                #pragma unroll
                for (int ks = 0; ks < 2; ++ks)
                    acc[mt][nt] = __builtin_amdgcn_mfma_f32_16x16x32_f16(
                        aF[mt][ks], bF[nt][ks], acc[mt][nt], 0, 0, 0);
        __syncthreads();
    }

    // ============ Transition: sigmoid -> Pn; zero sAcc ============
    // C/D layout: col(n)=l15, row = quad*4 + reg (+16*mt)
    #pragma unroll
    for (int nt = 0; nt < 6; ++nt) {
        int n = w * 96 + nt * 16 + l15;
        float bv = bias[n];
        #pragma unroll
        for (int mt = 0; mt < 2; ++mt) {
            int row = mt * 16 + quad * 4;
            H4 h;
            #pragma unroll
            for (int r = 0; r < 4; ++r) {
                float z = acc[mt][nt][r] + bv;
                h.h[r] = (_Float16)(1.0f / (1.0f + __expf(-z)));
            }
            *(ushort4*)(Pn + n * 40 + row) = h.u;
        }
    }
    #pragma unroll
    for (int j = 0; j < 9; ++j) {
        int idx = tid + 256 * j;
        if (idx < 32 * 66) sAcc[idx] = 0.f;
    }
    __syncthreads();

    // ================= Phase 2: trees =================
    f32x4 tac[2][4];
    #pragma unroll
    for (int mt = 0; mt < 2; ++mt)
        #pragma unroll
        for (int nt = 0; nt < 4; ++nt)
            tac[mt][nt] = (f32x4){0.f, 0.f, 0.f, 0.f};

    auto loadB = [&](int t, half8 (*bf)[2]) {
        #pragma unroll
        for (int nt = 0; nt < 4; ++nt)
            #pragma unroll
            for (int ks = 0; ks < 2; ++ks)
                bf[nt][ks] = *(const half8*)(V2 + (size_t)t * 4096 +
                                             (nt * 16 + l15) * 64 + ks * 32 + quad * 8);
    };
    const _Float16 one = (_Float16)1.0f;
    auto buildA = [&](int t, half8 (*af)[2]) {
        #pragma unroll
        for (int mt = 0; mt < 2; ++mt) {
            int rl = mt * 16 + l15;
            _Float16 p0 = Pn[(0 * 64 + t) * 40 + rl];
            _Float16 p1 = Pn[(1 * 64 + t) * 40 + rl];
            _Float16 p2 = Pn[(2 * 64 + t) * 40 + rl];
            _Float16 p3 = Pn[(3 * 64 + t) * 40 + rl];
            _Float16 p4 = Pn[(4 * 64 + t) * 40 + rl];
            _Float16 p5 = Pn[(5 * 64 + t) * 40 + rl];
            _Float16 q1 = (quad & 2) ? (_Float16)(one - p1) : p1;
            _Float16 q2 = (quad & 1) ? (_Float16)(one - p2) : p2;
            _Float16 pre  = q1 * q2;
            _Float16 pre0 = p0 * pre;
            _Float16 pre1 = (one - p0) * pre;
            h2v p4p = { p4, (_Float16)(one - p4) };
            h2v p5p = { p5, (_Float16)(one - p5) };
            h2v t34a = (h2v){ p3, p3 } * p4p;
            _Float16 p3b = one - p3;
            h2v t34b = (h2v){ p3b, p3b } * p4p;
            h2v w0 = (h2v){ t34a[0], t34a[0] } * p5p;
            h2v w1 = (h2v){ t34a[1], t34a[1] } * p5p;
            h2v w2 = (h2v){ t34b[0], t34b[0] } * p5p;
            h2v w3 = (h2v){ t34b[1], t34b[1] } * p5p;
            h2v P0 = { pre0, pre0 }, P1 = { pre1, pre1 };
            H8 a0, a1;
            *(h2v*)&a0.h[0] = P0 * w0; *(h2v*)&a0.h[2] = P0 * w1;
            *(h2v*)&a0.h[4] = P0 * w2; *(h2v*)&a0.h[6] = P0 * w3;
            *(h2v*)&a1.h[0] = P1 * w0; *(h2v*)&a1.h[2] = P1 * w1;
            *(h2v*)&a1.h[4] = P1 * w2; *(h2v*)&a1.h[6] = P1 * w3;
            af[mt][0] = a0.v;
            af[mt][1] = a1.v;
        }
    };

    half8 bA[4][2], bB[4][2], aF[2][2];
    loadB(w * 16, bA);
    for (int tl = 0; tl < 16; ++tl) {
        const int t = w * 16 + tl;
        half8 (*cur)[2] = (tl & 1) ? bB : bA;
        half8 (*nxt)[2] = (tl & 1) ? bA : bB;
        if (tl + 1 < 16) loadB(t + 1, nxt);   // in flight over the P build
        buildA(t, aF);
        #pragma unroll
        for (int mt = 0; mt < 2; ++mt)
            #pragma unroll
            for (int nt = 0; nt < 4; ++nt)
                #pragma unroll
                for (int ks = 0; ks < 2; ++ks)
                    tac[mt][nt] = __builtin_amdgcn_mfma_f32_16x16x32_f16(
                        aF[mt][ks], cur[nt][ks], tac[mt][nt], 0, 0, 0);
    }

    // cross-wave combine: LDS f32 atomics (<=2-way banks = free)
    #pragma unroll
    for (int mt = 0; mt < 2; ++mt)
        #pragma unroll
        for (int nt = 0; nt < 4; ++nt)
            #pragma unroll
            for (int r = 0; r < 4; ++r)
                atomicAdd(&sAcc[(mt * 16 + quad * 4 + r) * 66 + nt * 16 + l15],
                          tac[mt][nt][r]);
    __syncthreads();

    // final store: thread -> (row, 8 d's), coalesced float4 x2
    {
        int row = tid >> 3, d8 = (tid & 7) * 8;
        const float* s = sAcc + row * 66 + d8;
        float4 o0 = { s[0], s[1], s[2], s[3] };
        float4 o1 = { s[4], s[5], s[6], s[7] };
        float* dst = out + (size_t)(bm * 32 + row) * NDOUT + d8;
        *(float4*)dst = o0;
        *(float4*)(dst + 4) = o1;
    }
}

// ---------------------------------------------------------------------------
extern "C" void kernel_launch(void* const* d_in, const int* in_sizes, int n_in,
                              void* d_out, int out_size, void* d_ws, size_t ws_size,
                              hipStream_t stream) {
    const float* x    = (const float*)d_in[0];  // (16384, 512)
    const float* W    = (const float*)d_in[1];  // (6, 512, 64)
    const float* bias = (const float*)d_in[2];  // (6, 64) flat = 384
    const float* leaf = (const float*)d_in[3];  // (64, 64, 64)
    float* out = (float*)d_out;                 // (16384, 64)

    // ws: V2 f16 (512 KB) | Wt f16 (384 KB)
    _Float16* V2 = (_Float16*)d_ws;
    _Float16* Wt = V2 + (size_t)NTREE * NLEAF * NDOUT;

    prep<<<160, 256, 0, stream>>>(leaf, W, V2, Wt);
    fused<<<BATCH / 32, 256, 0, stream>>>(x, Wt, bias, V2, out);
}